// Round 9
// baseline (288.006 us; speedup 1.0000x reference)
//
#include <hip/hip_runtime.h>
#include <hip/hip_bf16.h>

// Problem: B=2, S=2048, D=1024, H=16, DK=64
// out = concat_heads(softmax(mask(qk^T))v) @ Wu + bu
// Inputs fp32 (mask int32), output fp32. Internal: bf16.
//
// R9: attn parallelism. 4 waves/block = (q-half, t-parity); both parity
// tiles staged per iteration (barriers halved), per-wave tile count halved,
// waves doubled (grid 1024 x 4 waves, 12 resident waves/CU at 50KB LDS).
// Unnormalized softmax is tile-linear -> in-block partial merge via LDS
// (f32, 36-float row pitch = 2-way banks). Transposed-score form as R8:
// S' = K.Q^T, P stored [q][t] b64, PV = P.V^T, O in C-layout.

typedef __bf16 bf16_t;
typedef __attribute__((ext_vector_type(4))) __bf16 bf16x4;
typedef __attribute__((ext_vector_type(8))) __bf16 bf16x8;
typedef __attribute__((ext_vector_type(4))) float f32x4;
typedef unsigned int u32;

#define B_ 2
#define S_ 2048
#define D_ 1024
#define H_ 16
#define DK_ 64
#define NX_ (4096 * 1024)

static __device__ __forceinline__ f32x4 mfma16(bf16x8 a, bf16x8 b, f32x4 c) {
  return __builtin_amdgcn_mfma_f32_16x16x32_bf16(a, b, c, 0, 0, 0);
}

// async global->LDS, 16B/lane; lds base wave-uniform, slot = base + lane*16
static __device__ __forceinline__ void async16(const bf16_t* g, bf16_t* l) {
  __builtin_amdgcn_global_load_lds(
      (const __attribute__((address_space(1))) u32*)g,
      (__attribute__((address_space(3))) u32*)l, 16, 0, 0);
}

// ---------------------------------------------------------------------------
// q/k/v fp32 -> bf16
// ---------------------------------------------------------------------------
__global__ __launch_bounds__(256) void cvt_x(const float* __restrict__ q,
                                             const float* __restrict__ k,
                                             const float* __restrict__ v,
                                             bf16_t* __restrict__ qo,
                                             bf16_t* __restrict__ ko,
                                             bf16_t* __restrict__ vo) {
  const int z = blockIdx.y;
  const float* src = (z == 0) ? q : (z == 1) ? k : v;
  bf16_t* dst = (z == 0) ? qo : (z == 1) ? ko : vo;
  size_t i = ((size_t)blockIdx.x * 256 + threadIdx.x) * 8;
  float4 a = *(const float4*)(src + i);
  float4 b = *(const float4*)(src + i + 4);
  bf16x8 o;
  o[0] = (bf16_t)a.x; o[1] = (bf16_t)a.y; o[2] = (bf16_t)a.z; o[3] = (bf16_t)a.w;
  o[4] = (bf16_t)b.x; o[5] = (bf16_t)b.y; o[6] = (bf16_t)b.z; o[7] = (bf16_t)b.w;
  *(bf16x8*)(dst + i) = o;
}

// ---------------------------------------------------------------------------
// Weight transpose -> n-major bf16 BT[n][d]. qk scale folded for z<=1.
// ---------------------------------------------------------------------------
__global__ __launch_bounds__(256) void wtrans(
    const float* __restrict__ Wq, const float* __restrict__ Wk,
    const float* __restrict__ Wv, const float* __restrict__ Wu,
    bf16_t* __restrict__ Bq, bf16_t* __restrict__ Bk,
    bf16_t* __restrict__ Bv, bf16_t* __restrict__ Bu, float qkscale) {
  __shared__ __align__(16) bf16_t T[64][72];
  const int z = blockIdx.z;
  const float* W = (z == 0) ? Wq : (z == 1) ? Wk : (z == 2) ? Wv : Wu;
  bf16_t* BT = (z == 0) ? Bq : (z == 1) ? Bk : (z == 2) ? Bv : Bu;
  const float scale = (z <= 1) ? qkscale : 1.0f;
  const int d0 = blockIdx.x * 64, nt = blockIdx.y;
  const int tid = threadIdx.x;
  const int r = tid & 63, g = tid >> 6;

  const float* src = (z < 3)
      ? W + ((size_t)nt * D_ + d0 + r) * DK_ + g * 16
      : W + (size_t)(d0 + r) * D_ + nt * 64 + g * 16;
#pragma unroll
  for (int j = 0; j < 4; ++j) {
    float4 w4 = *(const float4*)(src + j * 4);
    T[g * 16 + j * 4 + 0][r] = (bf16_t)(w4.x * scale);
    T[g * 16 + j * 4 + 1][r] = (bf16_t)(w4.y * scale);
    T[g * 16 + j * 4 + 2][r] = (bf16_t)(w4.z * scale);
    T[g * 16 + j * 4 + 3][r] = (bf16_t)(w4.w * scale);
  }
  __syncthreads();
  const int orow = tid >> 3, seg = tid & 7;
#pragma unroll
  for (int p = 0; p < 2; ++p) {
    int rr = p * 32 + orow;
    *(bf16x8*)(BT + (size_t)(nt * 64 + rr) * D_ + d0 + seg * 8) =
        *(const bf16x8*)&T[rr][seg * 8];
  }
}

// ---------------------------------------------------------------------------
// V [4096][1024] bf16 -> Vt [1024][4096] bf16 (LDS-tiled transpose)
// ---------------------------------------------------------------------------
__global__ __launch_bounds__(256) void vt_build(const bf16_t* __restrict__ V,
                                                bf16_t* __restrict__ Vt) {
  __shared__ __align__(16) bf16_t T[64][72];
  const int r0 = blockIdx.x * 64;  // s-dim
  const int c0 = blockIdx.y * 64;  // d-dim
  const int tid = threadIdx.x;
#pragma unroll
  for (int it = 0; it < 2; ++it) {
    int t = tid + it * 256;
    int rr = t >> 3, cc = (t & 7) * 8;
    *(bf16x8*)&T[rr][cc] = *(const bf16x8*)(V + (size_t)(r0 + rr) * D_ + c0 + cc);
  }
  __syncthreads();
#pragma unroll
  for (int it = 0; it < 2; ++it) {
    int t = tid + it * 256;
    int cr = t >> 3, rc = (t & 7) * 8;
    bf16x8 v;
#pragma unroll
    for (int j = 0; j < 8; ++j) v[j] = T[rc + j][cr];
    *(bf16x8*)(Vt + (size_t)(c0 + cr) * 4096 + r0 + rc) = v;
  }
}

// ---------------------------------------------------------------------------
// Pack mask [B,S,S] int32 -> bitfield (bit = mask != 0)
// ---------------------------------------------------------------------------
__global__ __launch_bounds__(256) void mask_pack(const int* __restrict__ mask,
                                                 unsigned int* __restrict__ bits) {
  int w = blockIdx.x * 256 + threadIdx.x;
  const int4* p = (const int4*)(mask + (size_t)w * 32);
  unsigned int v = 0;
#pragma unroll
  for (int i = 0; i < 8; ++i) {
    int4 m4 = p[i];
    v |= (m4.x != 0 ? 1u : 0u) << (i * 4 + 0);
    v |= (m4.y != 0 ? 1u : 0u) << (i * 4 + 1);
    v |= (m4.z != 0 ? 1u : 0u) << (i * 4 + 2);
    v |= (m4.w != 0 ? 1u : 0u) << (i * 4 + 3);
  }
  bits[w] = v;
}

// ---------------------------------------------------------------------------
// GEMM 128x128: C[4096,1024] = A @ BT^T, BK=64, XOR-swizzled LDS. (qkv, z=3)
// ---------------------------------------------------------------------------
__global__ __launch_bounds__(256) void gemm_bt(
    const bf16_t* __restrict__ A0, const bf16_t* __restrict__ A1,
    const bf16_t* __restrict__ A2, const bf16_t* __restrict__ BT0,
    const bf16_t* __restrict__ BT1, const bf16_t* __restrict__ BT2,
    bf16_t* __restrict__ C0, bf16_t* __restrict__ C1, bf16_t* __restrict__ C2) {
  __shared__ __align__(16) bf16_t As[128 * 64];
  __shared__ __align__(16) bf16_t Bs[128 * 64];

  const int z = blockIdx.z;
  const bf16_t* A = (z == 0) ? A0 : (z == 1) ? A1 : A2;
  const bf16_t* BT = (z == 0) ? BT0 : (z == 1) ? BT1 : BT2;
  bf16_t* C = (z == 0) ? C0 : (z == 1) ? C1 : C2;

  const int tid = threadIdx.x;
  const int lane = tid & 63, wave = tid >> 6;
  const int l = lane & 15, quad = lane >> 4;
  const int wm = wave >> 1, wn = wave & 1;
  const int row0 = blockIdx.x * 128, col0 = blockIdx.y * 128;

  const int lr = lane >> 3;
  const int gc8 = (lane & 7) ^ lr;
  const int xl = l & 7;

  f32x4 acc[4][4];
#pragma unroll
  for (int i = 0; i < 4; ++i)
#pragma unroll
    for (int j = 0; j < 4; ++j) acc[i][j] = {0.f, 0.f, 0.f, 0.f};

  for (int k0 = 0; k0 < 1024; k0 += 64) {
    __syncthreads();
#pragma unroll
    for (int c = 0; c < 4; ++c) {
      int r = wave * 32 + c * 8;
      async16(A + (size_t)(row0 + r + lr) * 1024 + k0 + gc8 * 8, As + r * 64);
      async16(BT + (size_t)(col0 + r + lr) * 1024 + k0 + gc8 * 8, Bs + r * 64);
    }
    __syncthreads();

#pragma unroll
    for (int kh = 0; kh < 2; ++kh) {
      bf16x8 af[4], bf[4];
#pragma unroll
      for (int f = 0; f < 4; ++f)
        af[f] = *(const bf16x8*)&As[(wm * 64 + f * 16 + l) * 64 +
                                    (((kh * 4 + quad) ^ xl) * 8)];
#pragma unroll
      for (int f = 0; f < 4; ++f)
        bf[f] = *(const bf16x8*)&Bs[(wn * 64 + f * 16 + l) * 64 +
                                    (((kh * 4 + quad) ^ xl) * 8)];
#pragma unroll
      for (int fm = 0; fm < 4; ++fm)
#pragma unroll
        for (int fn = 0; fn < 4; ++fn)
          acc[fm][fn] = mfma16(af[fm], bf[fn], acc[fm][fn]);
    }
  }

#pragma unroll
  for (int fm = 0; fm < 4; ++fm)
#pragma unroll
    for (int fn = 0; fn < 4; ++fn)
#pragma unroll
      for (int reg = 0; reg < 4; ++reg) {
        int row = row0 + wm * 64 + fm * 16 + quad * 4 + reg;
        int col = col0 + wn * 64 + fn * 16 + l;
        C[(size_t)row * 1024 + col] = (bf16_t)acc[fm][fn][reg];
      }
}

// ---------------------------------------------------------------------------
// GEMM 64x128 (out-proj): out = A @ BT^T + bias, fp32 out. 512 blocks.
// ---------------------------------------------------------------------------
__global__ __launch_bounds__(256) void gemm_bt64(
    const bf16_t* __restrict__ A, const bf16_t* __restrict__ BT,
    float* __restrict__ C, const float* __restrict__ bias) {
  __shared__ __align__(16) bf16_t As[64 * 64];
  __shared__ __align__(16) bf16_t Bs[128 * 64];

  const int tid = threadIdx.x;
  const int lane = tid & 63, wave = tid >> 6;
  const int l = lane & 15, quad = lane >> 4;
  const int row0 = blockIdx.x * 64, col0 = blockIdx.y * 128;

  const int lr = lane >> 3;
  const int gc8 = (lane & 7) ^ lr;
  const int xl = l & 7;

  f32x4 acc[4][2];
#pragma unroll
  for (int i = 0; i < 4; ++i)
#pragma unroll
    for (int j = 0; j < 2; ++j) acc[i][j] = {0.f, 0.f, 0.f, 0.f};

  for (int k0 = 0; k0 < 1024; k0 += 64) {
    __syncthreads();
#pragma unroll
    for (int c = 0; c < 2; ++c) {
      int r = wave * 16 + c * 8;
      async16(A + (size_t)(row0 + r + lr) * 1024 + k0 + gc8 * 8, As + r * 64);
    }
#pragma unroll
    for (int c = 0; c < 4; ++c) {
      int r = wave * 32 + c * 8;
      async16(BT + (size_t)(col0 + r + lr) * 1024 + k0 + gc8 * 8, Bs + r * 64);
    }
    __syncthreads();

#pragma unroll
    for (int kh = 0; kh < 2; ++kh) {
      bf16x8 af[4], bf[2];
#pragma unroll
      for (int f = 0; f < 4; ++f)
        af[f] = *(const bf16x8*)&As[(f * 16 + l) * 64 +
                                    (((kh * 4 + quad) ^ xl) * 8)];
#pragma unroll
      for (int f = 0; f < 2; ++f)
        bf[f] = *(const bf16x8*)&Bs[(wave * 32 + f * 16 + l) * 64 +
                                    (((kh * 4 + quad) ^ xl) * 8)];
#pragma unroll
      for (int fm = 0; fm < 4; ++fm)
#pragma unroll
        for (int fn = 0; fn < 2; ++fn)
          acc[fm][fn] = mfma16(af[fm], bf[fn], acc[fm][fn]);
    }
  }

#pragma unroll
  for (int fm = 0; fm < 4; ++fm)
#pragma unroll
    for (int fn = 0; fn < 2; ++fn)
#pragma unroll
      for (int reg = 0; reg < 4; ++reg) {
        int row = row0 + fm * 16 + quad * 4 + reg;
        int col = col0 + wave * 32 + fn * 16 + l;
        C[(size_t)row * 1024 + col] = acc[fm][fn][reg] + bias[col];
      }
}

// ---------------------------------------------------------------------------
// Flash attention, transposed-score, 4 waves = (q-half, t-parity).
// Per iteration both parity K/V tiles are staged; wave (qh,p) processes
// tile t0+p*64 for q rows qt*64+qh*32..+31. Partials merged in-block.
// ---------------------------------------------------------------------------
__global__ __launch_bounds__(256) void attn_kernel(
    const bf16_t* __restrict__ Qx, const bf16_t* __restrict__ Kx,
    const bf16_t* __restrict__ Vt, const unsigned int* __restrict__ mbits,
    bf16_t* __restrict__ out) {
  // KVs[0..1] = K parity 0/1 [t][dk]; KVs[2..3] = V^T parity 0/1 [d][t]
  __shared__ __align__(16) bf16_t KVs[4][64 * 64];
  __shared__ __align__(16) bf16_t Ps[4][32][72];  // per-wave P [q][t]

  const int tid = threadIdx.x;
  const int lane = tid & 63, wave = tid >> 6;  // 4 waves
  const int l = lane & 15, quad = lane >> 4;
  const int qh = wave & 1, p = wave >> 1;
  const int qt = blockIdx.x, h = blockIdx.y, b = blockIdx.z;
  const int ch = h * 64;
  const size_t rb = (size_t)b * S_;
  const int q0 = qt * 64 + qh * 32;

  const int lr = lane >> 3;
  const int gc8 = (lane & 7) ^ lr;
  const int xl = l & 7;

  // Q B-frags: bq[mf][kc], B[n=q=l][k=dk]
  bf16x8 bq[2][2];
#pragma unroll
  for (int mf = 0; mf < 2; ++mf) {
    const bf16_t* qp = Qx + (rb + q0 + mf * 16 + l) * D_ + ch;
    bq[mf][0] = *(const bf16x8*)(qp + quad * 8);
    bq[mf][1] = *(const bf16x8*)(qp + 32 + quad * 8);
  }

  const f32x4 zero = {0.f, 0.f, 0.f, 0.f};
  f32x4 o[2][4];  // O[q][d] partial (this wave's t-parity)
  float lsum[2] = {0.f, 0.f};
#pragma unroll
  for (int mf = 0; mf < 2; ++mf)
#pragma unroll
    for (int nt = 0; nt < 4; ++nt) o[mf][nt] = zero;

  const u32* mrow[2];
#pragma unroll
  for (int mf = 0; mf < 2; ++mf)
    mrow[mf] = mbits + (size_t)(b * S_ + q0 + mf * 16 + l) * (S_ / 32);

  const bf16_t* Kp = KVs[p];
  const bf16_t* Vp = KVs[2 + p];

  for (int t0 = 0; t0 < S_; t0 += 128) {
    __syncthreads();
    // stage 4 buffers; wave w stages buffer w (8 rows x 8 rounds, uniform)
#pragma unroll
    for (int j = 0; j < 8; ++j) {
      int r0 = j * 8;
      if (wave < 2)
        async16(Kx + (rb + t0 + qh * 64 + r0 + lr) * D_ + ch + gc8 * 8,
                KVs[wave] + r0 * 64);
      else
        async16(Vt + (size_t)(ch + r0 + lr) * 4096 + rb + t0 + qh * 64 + gc8 * 8,
                KVs[wave] + r0 * 64);
    }
    __syncthreads();

    const int tw = t0 + p * 64;
    // S' = K.Q^T per (mf, ts): D[m=t=quad*4+reg][n=q=l]
#pragma unroll
    for (int mf = 0; mf < 2; ++mf) {
      u32 mw0 = mrow[mf][(tw >> 5)];
      u32 mw1 = mrow[mf][(tw >> 5) + 1];
#pragma unroll
      for (int ts = 0; ts < 4; ++ts) {
        int rK = (ts * 16 + l) * 64;
        bf16x8 ak0 = *(const bf16x8*)&Kp[rK + ((quad ^ xl) * 8)];
        bf16x8 ak1 = *(const bf16x8*)&Kp[rK + (((4 + quad) ^ xl) * 8)];
        f32x4 s = mfma16(ak0, bq[mf][0], zero);
        s = mfma16(ak1, bq[mf][1], s);

        u32 mw = (ts < 2) ? mw0 : mw1;
        u32 nib = (mw >> ((ts & 1) * 16 + quad * 4)) & 0xFu;
        bf16x4 pv;
#pragma unroll
        for (int reg = 0; reg < 4; ++reg) {
          float e = __expf(fminf(s[reg], 30.0f));
          float pp = ((nib >> reg) & 1u) ? e : 0.0f;
          lsum[mf] += pp;
          pv[reg] = (bf16_t)pp;
        }
        *(bf16x4*)&Ps[wave][mf * 16 + l][ts * 16 + quad * 4] = pv;
      }
    }

    // PV: O[q][d] += P.V^T (per-wave Ps, in-order DS per wave)
    bf16x8 ap[2][2];
#pragma unroll
    for (int mf = 0; mf < 2; ++mf) {
      ap[mf][0] = *(const bf16x8*)&Ps[wave][mf * 16 + l][quad * 8];
      ap[mf][1] = *(const bf16x8*)&Ps[wave][mf * 16 + l][32 + quad * 8];
    }
#pragma unroll
    for (int nt = 0; nt < 4; ++nt) {
      int rV = (nt * 16 + l) * 64;
      bf16x8 bv0 = *(const bf16x8*)&Vp[rV + ((quad ^ xl) * 8)];
      bf16x8 bv1 = *(const bf16x8*)&Vp[rV + (((4 + quad) ^ xl) * 8)];
#pragma unroll
      for (int mf = 0; mf < 2; ++mf) {
        o[mf][nt] = mfma16(ap[mf][0], bv0, o[mf][nt]);
        o[mf][nt] = mfma16(ap[mf][1], bv1, o[mf][nt]);
      }
    }
  }

  // merge parities in-block: p=1 waves publish partials (f32, pitch 36 for
  // 2-way banks), p=0 waves add and finish.
  __syncthreads();
  float* Sm = (float*)KVs;  // 32KB scratch
  const int mrow36 = (qh * 64 + lane) * 36;
  if (p == 1) {
#pragma unroll
    for (int mf = 0; mf < 2; ++mf) {
#pragma unroll
      for (int nt = 0; nt < 4; ++nt)
        *(f32x4*)&Sm[mrow36 + (mf * 4 + nt) * 4] = o[mf][nt];
      Sm[mrow36 + 32 + mf] = lsum[mf];
    }
  }
  __syncthreads();
  if (p == 0) {
#pragma unroll
    for (int mf = 0; mf < 2; ++mf) {
#pragma unroll
      for (int nt = 0; nt < 4; ++nt) {
        f32x4 t = *(const f32x4*)&Sm[mrow36 + (mf * 4 + nt) * 4];
#pragma unroll
        for (int r = 0; r < 4; ++r) o[mf][nt][r] += t[r];
      }
      lsum[mf] += Sm[mrow36 + 32 + mf];
    }
    // epilogue: reduce row sums over quads (q=l), broadcast inv, write bf16
#pragma unroll
    for (int mf = 0; mf < 2; ++mf) {
      float rsum = lsum[mf];
      rsum += __shfl_xor(rsum, 16);
      rsum += __shfl_xor(rsum, 32);
      float inv = (rsum > 0.f) ? (1.f / rsum) : 0.f;
      float invr[4];
#pragma unroll
      for (int reg = 0; reg < 4; ++reg) invr[reg] = __shfl(inv, quad * 4 + reg);
#pragma unroll
      for (int reg = 0; reg < 4; ++reg) {
        int srow = q0 + mf * 16 + quad * 4 + reg;
        bf16_t* op = out + (rb + srow) * D_ + ch;
#pragma unroll
        for (int nt = 0; nt < 4; ++nt)
          op[nt * 16 + l] = (bf16_t)(o[mf][nt][reg] * invr[reg]);
      }
    }
  }
}

// ---------------------------------------------------------------------------
extern "C" void kernel_launch(void* const* d_in, const int* in_sizes, int n_in,
                              void* d_out, int out_size, void* d_ws, size_t ws_size,
                              hipStream_t stream) {
  const float* q_in = (const float*)d_in[0];
  const float* k_in = (const float*)d_in[1];
  const float* v_in = (const float*)d_in[2];
  const int* mask = (const int*)d_in[3];
  const float* Wq = (const float*)d_in[4];
  const float* Wk = (const float*)d_in[5];
  const float* Wv = (const float*)d_in[6];
  const float* Wu = (const float*)d_in[7];
  const float* bu = (const float*)d_in[8];
  float* outp = (float*)d_out;

  bf16_t* qx = (bf16_t*)d_ws;
  bf16_t* kx = qx + NX_;
  bf16_t* vx = kx + NX_;
  bf16_t* qb = vx + NX_;
  bf16_t* kb = qb + NX_;
  bf16_t* vb = kb + NX_;
  bf16_t* BTq = vb + NX_;
  bf16_t* BTk = BTq + D_ * D_;
  bf16_t* BTv = BTk + D_ * D_;
  bf16_t* BTu = BTv + D_ * D_;
  unsigned int* mb = (unsigned int*)(BTu + D_ * D_);
  bf16_t* ab = qx;   // qx dead after qkv gemm
  bf16_t* vtb = kx;  // kx dead after qkv gemm

  const float qkscale = 0.35355339059327373f;  // 1 / 64^0.25

  dim3 blk(256);
  cvt_x<<<dim3(2048, 3), blk, 0, stream>>>(q_in, k_in, v_in, qx, kx, vx);
  wtrans<<<dim3(16, 16, 4), blk, 0, stream>>>(Wq, Wk, Wv, Wu, BTq, BTk, BTv, BTu, qkscale);
  mask_pack<<<dim3(1024), blk, 0, stream>>>(mask, mb);
  gemm_bt<<<dim3(32, 8, 3), blk, 0, stream>>>(qx, kx, vx, BTq, BTk, BTv,
                                              qb, kb, vb);
  vt_build<<<dim3(64, 16), blk, 0, stream>>>(vb, vtb);
  attn_kernel<<<dim3(S_ / 64, H_, B_), blk, 0, stream>>>(qb, kb, vtb, mb, ab);
  gemm_bt64<<<dim3(64, 8), blk, 0, stream>>>(ab, BTu, outp, bu);
}